// Round 2
// baseline (308.357 us; speedup 1.0000x reference)
//
#include <hip/hip_runtime.h>

// Problem constants
#define NHEADS   8
#define EMB_     128
#define BT_      512        // b*t = 4*128
#define HIN_     1024
#define NQ_      4096       // BT_*NHEADS
#define NKEY_    50000
#define NPAD_    50048      // 782 tiles of 64 keys
#define TILES_TOT 782
#define TPS_     13         // key tiles per slice
#define NSLICES_ 64         // 60 full + 1 partial (2 tiles) + 3 empty -> grid 16x64 = 4 blk/CU

// scale = 128^-0.25 (reference) * log2(e) (scores land directly in exp2 domain)
#define QSCALE   (0.29730177875068026f * 1.4426950408889634f)
#define SHIFT_   44.0f      // fixed softmax shift in log2 domain (> max score ~30 bits)

typedef __attribute__((ext_vector_type(8))) short short8v;   // 8 bf16 = 4 VGPRs (MFMA A/B frag)
typedef __attribute__((ext_vector_type(4))) float float4v;   // MFMA C/D frag

#if __has_builtin(__builtin_amdgcn_exp2f)
#define EXP2F(x) __builtin_amdgcn_exp2f(x)
#else
#define EXP2F(x) exp2f(x)
#endif

__device__ __forceinline__ short f2bf(float f) {  // fp32 -> bf16 bits, RNE
  unsigned u = __float_as_uint(f);
  u += 0x7fffu + ((u >> 16) & 1u);
  return (short)(u >> 16);
}

// async 16B global->LDS (DMA; LDS dest must be wave-uniform base + lane*16)
__device__ __forceinline__ void gld_lds16(const void* g, void* l) {
  __builtin_amdgcn_global_load_lds((const __attribute__((address_space(1))) void*)g,
                                   (__attribute__((address_space(3))) void*)l, 16, 0, 0);
}

// ---------------------------------------------------------------------------
// Kernel 0: keys fp32 -> bf16 with XOR chunk swizzle + zero-pad; values padded.
// Physical 16B chunk p of row `key` holds logical chunk (p ^ (key&15)) so the
// attention B-frag ds_read_b128 is 2-way max (free, m136) with NO padding
// (keeps the layout global_load_lds-compatible).
// ---------------------------------------------------------------------------
__global__ __launch_bounds__(256) void convert_kernel(
    const float* __restrict__ keys, const float* __restrict__ values,
    short* __restrict__ keys_sw, float* __restrict__ vpad) {
  int idx = blockIdx.x * 256 + threadIdx.x;      // one thread per 8-elem chunk
  if (idx >= NPAD_ * 16) return;
  int key = idx >> 4;
  int p   = idx & 15;
  int lc  = p ^ (key & 15);                      // logical chunk stored here
  short8v o;
  if (key < NKEY_) {
    const float* src = keys + key * EMB_ + lc * 8;
#pragma unroll
    for (int i = 0; i < 8; ++i) o[i] = f2bf(src[i]);
  } else {
#pragma unroll
    for (int i = 0; i < 8; ++i) o[i] = 0;        // pad rows: score 0 -> p=2^-44, negligible
  }
  *(short8v*)(keys_sw + idx * 8) = o;            // coalesced 16B stores
  if (p == 0) vpad[key] = (key < NKEY_) ? values[key] : 0.f;
}

// ---------------------------------------------------------------------------
// Kernel 1: q = (x @ Wq^T) * QSCALE -> bf16 [BT_][1024]. One 16x16 output tile
// per wave via mfma_16x16x32_bf16, K=1024 streamed straight from global fp32
// with inline bf16 convert (x 2MB / Wq 4MB are L2-resident; no LDS, no
// barriers -> no bank conflicts, no sync stalls).
//   A[m=ln][k=quad*8+j] = x[mt*16+ln][k0+quad*8+j]
//   B[n=ln][k=quad*8+j] = Wq[ot*16+ln][k0+quad*8+j]
//   D row=quad*4+r2, col=ln
// ---------------------------------------------------------------------------
__global__ __launch_bounds__(256) void proj_kernel(
    const float* __restrict__ x, const float* __restrict__ Wq,
    short* __restrict__ qb) {
  const int wave = threadIdx.x >> 6, lane = threadIdx.x & 63;
  const int quad = lane >> 4, ln = lane & 15;
  const int tile = blockIdx.x * 4 + wave;        // 2048 tiles
  const int mt = tile >> 6, ot = tile & 63;      // 32 m-tiles x 64 o-tiles
  const float* xrow = x  + (mt * 16 + ln) * HIN_ + quad * 8;
  const float* wrow = Wq + (ot * 16 + ln) * HIN_ + quad * 8;
  float4v d = {0.f, 0.f, 0.f, 0.f};
#pragma unroll 4
  for (int k0 = 0; k0 < HIN_; k0 += 32) {
    float4 xa = *(const float4*)(xrow + k0);
    float4 xb = *(const float4*)(xrow + k0 + 4);
    float4 wa = *(const float4*)(wrow + k0);
    float4 wb = *(const float4*)(wrow + k0 + 4);
    short8v af, bf;
    af[0]=f2bf(xa.x); af[1]=f2bf(xa.y); af[2]=f2bf(xa.z); af[3]=f2bf(xa.w);
    af[4]=f2bf(xb.x); af[5]=f2bf(xb.y); af[6]=f2bf(xb.z); af[7]=f2bf(xb.w);
    bf[0]=f2bf(wa.x); bf[1]=f2bf(wa.y); bf[2]=f2bf(wa.z); bf[3]=f2bf(wa.w);
    bf[4]=f2bf(wb.x); bf[5]=f2bf(wb.y); bf[6]=f2bf(wb.z); bf[7]=f2bf(wb.w);
    d = __builtin_amdgcn_mfma_f32_16x16x32_bf16(af, bf, d, 0, 0, 0);
  }
#pragma unroll
  for (int r2 = 0; r2 < 4; ++r2)
    qb[(mt * 16 + quad * 4 + r2) * HIN_ + ot * 16 + ln] = f2bf(d[r2] * QSCALE);
}

// ---------------------------------------------------------------------------
// Kernel 2: flash-decoding attention. Grid (16 query-cols, 64 key-slices) =
// 1024 blocks = 4 blocks/CU. Per WG: 256 queries (4 waves x 4 sub-tiles,
// A-frags register-resident), stream 64-key tiles into LDS via
// global_load_lds (16B DMA, lane-linear dest). MFMA accumulator is
// initialized to -SHIFT_ so the epilogue is exp2 + add + fma only.
// ---------------------------------------------------------------------------
__global__ __launch_bounds__(256, 4) void attn_kernel(
    const short* __restrict__ qb,        // bf16 [NQ_][128]
    const short* __restrict__ keys_sw,   // bf16 [NPAD_][128], chunk-swizzled
    const float* __restrict__ vpad,      // [NPAD_]
    float* __restrict__ partials) {      // [NQ_][NSLICES_][2] = {l, acc}
  __shared__ __align__(16) short kt[64 * 128];   // 16 KB key tile
  const int t     = threadIdx.x;
  const int wave  = t >> 6;
  const int lane  = t & 63;
  const int quad  = lane >> 4;
  const int ln    = lane & 15;
  const int qbase = blockIdx.x * 256 + wave * 64;
  const int slice = blockIdx.y;
  const int tile0 = slice * TPS_;
  const int tile1 = (tile0 + TPS_ < TILES_TOT) ? (tile0 + TPS_) : TILES_TOT;

  // A fragments, register resident: a[sub][ks] covers q rows qbase+sub*16+ln
  short8v a[4][4];
#pragma unroll
  for (int sub = 0; sub < 4; ++sub)
#pragma unroll
    for (int ks = 0; ks < 4; ++ks)
      a[sub][ks] = *(const short8v*)(qb + (qbase + sub * 16 + ln) * EMB_ + ks * 32 + quad * 8);

  float lsum[4][4], asum[4][4];
#pragma unroll
  for (int i = 0; i < 4; ++i)
#pragma unroll
    for (int j = 0; j < 4; ++j) { lsum[i][j] = 0.f; asum[i][j] = 0.f; }

  for (int tile = tile0; tile < tile1; ++tile) {
    __syncthreads();
    const short* src = keys_sw + tile * (64 * 128);
#pragma unroll
    for (int j = 0; j < 4; ++j) {                // 16 KB: 256 thr x 4 x 16B DMA
      int cidx = t + j * 256;                    // LDS byte = wg-uniform + lane*16: OK
      gld_lds16(src + cidx * 8, kt + cidx * 8);
    }
    __syncthreads();                             // drains vmcnt (incl. lds-DMA)

#pragma unroll
    for (int nsub = 0; nsub < 4; ++nsub) {
      short8v b[4];
#pragma unroll
      for (int ks = 0; ks < 4; ++ks) {
        int kc = ks * 4 + quad;                  // logical 8-elem chunk
        b[ks] = *(const short8v*)(kt + (nsub * 16 + ln) * EMB_ + ((kc ^ ln) * 8));
      }
      float v = vpad[tile * 64 + nsub * 16 + ln];  // value for this lane's key column
#pragma unroll
      for (int sub = 0; sub < 4; ++sub) {
        float4v d = {-SHIFT_, -SHIFT_, -SHIFT_, -SHIFT_};  // fold softmax shift into C
#pragma unroll
        for (int ks = 0; ks < 4; ++ks)
          d = __builtin_amdgcn_mfma_f32_16x16x32_bf16(a[sub][ks], b[ks], d, 0, 0, 0);
#pragma unroll
        for (int r2 = 0; r2 < 4; ++r2) {
          float p = EXP2F(d[r2]);
          lsum[sub][r2] += p;
          asum[sub][r2] = fmaf(p, v, asum[sub][r2]);
        }
      }
    }
  }

  // reduce over the 16 key-column lanes (same quad), then lane ln==0 writes.
  // Empty slices (61..63) still write zeros -- finalize reads all 64.
#pragma unroll
  for (int sub = 0; sub < 4; ++sub)
#pragma unroll
    for (int r2 = 0; r2 < 4; ++r2) {
      float L = lsum[sub][r2], A = asum[sub][r2];
#pragma unroll
      for (int m = 1; m < 16; m <<= 1) {
        L += __shfl_xor(L, m, 64);
        A += __shfl_xor(A, m, 64);
      }
      if (ln == 0) {
        int q = qbase + sub * 16 + quad * 4 + r2;
        partials[(q * NSLICES_ + slice) * 2 + 0] = L;
        partials[(q * NSLICES_ + slice) * 2 + 1] = A;
      }
    }
}

// ---------------------------------------------------------------------------
// Kernel 3: combine slice partials, mean over heads, add curiosity.
// One thread per (bt, head); float4 loads (per-thread data is contiguous).
// ---------------------------------------------------------------------------
__global__ __launch_bounds__(256) void finalize_kernel(
    const float* __restrict__ partials, const float* __restrict__ cur,
    float* __restrict__ out) {
  int tid = blockIdx.x * 256 + threadIdx.x;      // 4096 threads
  int bt = tid >> 3, h = tid & 7;
  int q = bt * NHEADS + h;
  const float4* p = (const float4*)(partials + q * NSLICES_ * 2);
  float sl = 0.f, sa = 0.f;
#pragma unroll 8
  for (int i = 0; i < NSLICES_ / 2; ++i) {       // 2 slices per float4
    float4 v = p[i];
    sl += v.x + v.z;
    sa += v.y + v.w;
  }
  float r = sa / sl;
  r += __shfl_xor(r, 1, 64);
  r += __shfl_xor(r, 2, 64);
  r += __shfl_xor(r, 4, 64);
  if (h == 0) out[bt] = r * (1.f / NHEADS) + cur[bt];
}

// ---------------------------------------------------------------------------
extern "C" void kernel_launch(void* const* d_in, const int* in_sizes, int n_in,
                              void* d_out, int out_size, void* d_ws, size_t ws_size,
                              hipStream_t stream) {
  (void)in_sizes; (void)n_in; (void)out_size; (void)ws_size;
  const float* x      = (const float*)d_in[0];   // (4,128,1024)
  const float* cur    = (const float*)d_in[1];   // (4,128)
  const float* Wq     = (const float*)d_in[2];   // (1024,1024)
  const float* keys   = (const float*)d_in[3];   // (50000,128)
  const float* values = (const float*)d_in[4];   // (50000,)
  float* out = (float*)d_out;                    // (4,128,1) fp32

  // workspace layout (16B-aligned), ~16.2 MB total
  char* ws = (char*)d_ws;
  short* keys_sw = (short*)(ws);                        // 12,812,288 B
  float* vpad    = (float*)(ws + 12812288);             //    200,192 B
  short* qb      = (short*)(ws + 13012480);             //  1,048,576 B
  float* part    = (float*)(ws + 14061056);             //  2,097,152 B (64 slices)

  hipLaunchKernelGGL(convert_kernel, dim3((NPAD_ * 16) / 256), dim3(256), 0, stream,
                     keys, values, keys_sw, vpad);
  hipLaunchKernelGGL(proj_kernel, dim3(512), dim3(256), 0, stream, x, Wq, qb);
  hipLaunchKernelGGL(attn_kernel, dim3(16, NSLICES_), dim3(256), 0, stream,
                     qb, keys_sw, vpad, part);
  hipLaunchKernelGGL(finalize_kernel, dim3(16), dim3(256), 0, stream, part, cur, out);
}

// Round 3
// 287.171 us; speedup vs baseline: 1.0738x; 1.0738x over previous
//
#include <hip/hip_runtime.h>

// Problem constants
#define NHEADS   8
#define EMB_     128
#define BT_      512        // b*t = 4*128
#define HIN_     1024
#define NQ_      4096       // BT_*NHEADS
#define NKEY_    50000
#define NPAD_    50048      // 782 tiles of 64 keys
#define TILES_TOT 782
#define TPS_     13         // key tiles per slice
#define NSLICES_ 64         // 60 full + 1 partial (2 tiles) + 3 empty

// scale = 128^-0.25 (reference) * log2(e) (scores land directly in exp2 domain)
#define QSCALE   (0.29730177875068026f * 1.4426950408889634f)
#define SHIFT_   44.0f      // fixed softmax shift in log2 domain (> max score)

typedef __attribute__((ext_vector_type(8))) short short8v;   // 8 bf16 = 4 VGPRs (MFMA A/B frag)
typedef __attribute__((ext_vector_type(4))) float float4v;   // MFMA C/D frag

#if __has_builtin(__builtin_amdgcn_exp2f)
#define EXP2F(x) __builtin_amdgcn_exp2f(x)
#else
#define EXP2F(x) exp2f(x)
#endif

__device__ __forceinline__ short f2bf(float f) {  // fp32 -> bf16 bits, RNE
  unsigned u = __float_as_uint(f);
  u += 0x7fffu + ((u >> 16) & 1u);
  return (short)(u >> 16);
}

// ---------------------------------------------------------------------------
// Kernel 0: keys fp32 -> bf16 with XOR chunk swizzle + zero-pad; values padded.
// Physical 16B chunk p of row `key` holds logical chunk (p ^ (key&15)) so the
// attention B-frag ds_read_b128 is 2-way max (free, m136) with NO padding.
// ---------------------------------------------------------------------------
__global__ __launch_bounds__(256) void convert_kernel(
    const float* __restrict__ keys, const float* __restrict__ values,
    short* __restrict__ keys_sw, float* __restrict__ vpad) {
  int idx = blockIdx.x * 256 + threadIdx.x;      // one thread per 8-elem chunk
  if (idx >= NPAD_ * 16) return;
  int key = idx >> 4;
  int p   = idx & 15;
  int lc  = p ^ (key & 15);                      // logical chunk stored here
  short8v o;
  if (key < NKEY_) {
    const float* src = keys + key * EMB_ + lc * 8;
#pragma unroll
    for (int i = 0; i < 8; ++i) o[i] = f2bf(src[i]);
  } else {
#pragma unroll
    for (int i = 0; i < 8; ++i) o[i] = 0;        // pad rows: score 0 -> p=2^-44, negligible
  }
  *(short8v*)(keys_sw + idx * 8) = o;            // coalesced 16B stores
  if (p == 0) vpad[key] = (key < NKEY_) ? values[key] : 0.f;
}

// ---------------------------------------------------------------------------
// Kernel 1: q = (x @ Wq^T) * QSCALE -> bf16 [BT_][1024]. One 16x16 output tile
// per wave via mfma_16x16x32_bf16, K=1024 streamed from global fp32 with
// inline bf16 convert (x/Wq L2-resident; no LDS, no barriers).
// ---------------------------------------------------------------------------
__global__ __launch_bounds__(256) void proj_kernel(
    const float* __restrict__ x, const float* __restrict__ Wq,
    short* __restrict__ qb) {
  const int wave = threadIdx.x >> 6, lane = threadIdx.x & 63;
  const int quad = lane >> 4, ln = lane & 15;
  const int tile = blockIdx.x * 4 + wave;        // 2048 tiles
  const int mt = tile >> 6, ot = tile & 63;      // 32 m-tiles x 64 o-tiles
  const float* xrow = x  + (mt * 16 + ln) * HIN_ + quad * 8;
  const float* wrow = Wq + (ot * 16 + ln) * HIN_ + quad * 8;
  float4v d = {0.f, 0.f, 0.f, 0.f};
#pragma unroll 4
  for (int k0 = 0; k0 < HIN_; k0 += 32) {
    float4 xa = *(const float4*)(xrow + k0);
    float4 xb = *(const float4*)(xrow + k0 + 4);
    float4 wa = *(const float4*)(wrow + k0);
    float4 wb = *(const float4*)(wrow + k0 + 4);
    short8v af, bf;
    af[0]=f2bf(xa.x); af[1]=f2bf(xa.y); af[2]=f2bf(xa.z); af[3]=f2bf(xa.w);
    af[4]=f2bf(xb.x); af[5]=f2bf(xb.y); af[6]=f2bf(xb.z); af[7]=f2bf(xb.w);
    bf[0]=f2bf(wa.x); bf[1]=f2bf(wa.y); bf[2]=f2bf(wa.z); bf[3]=f2bf(wa.w);
    bf[4]=f2bf(wb.x); bf[5]=f2bf(wb.y); bf[6]=f2bf(wb.z); bf[7]=f2bf(wb.w);
    d = __builtin_amdgcn_mfma_f32_16x16x32_bf16(af, bf, d, 0, 0, 0);
  }
#pragma unroll
  for (int r2 = 0; r2 < 4; ++r2)
    qb[(mt * 16 + quad * 4 + r2) * HIN_ + ot * 16 + ln] = f2bf(d[r2] * QSCALE);
}

// ---------------------------------------------------------------------------
// Kernel 2: flash-decoding attention. Grid (16 query-cols, 64 key-slices) =
// 1024 blocks. Per WG: 256 queries (4 waves x 4 sub-tiles, A-frags register-
// resident). Key tiles staged via vector loads with REGISTER PREFETCH:
// while computing tile k from LDS, tile k+1's 64B/thread sits in stage regs
// (global latency hidden behind MFMA+epilogue). No global_load_lds (round-2's
// 525 MB FETCH / 175 MB WRITE anomaly traced to that path + 64-VGPR cap).
// launch_bounds(256,3): 170-VGPR budget fits A(64)+sums(32)+stage(16)+B(16).
// ---------------------------------------------------------------------------
__global__ __launch_bounds__(256, 3) void attn_kernel(
    const short* __restrict__ qb,        // bf16 [NQ_][128]
    const short* __restrict__ keys_sw,   // bf16 [NPAD_][128], chunk-swizzled
    const float* __restrict__ vpad,      // [NPAD_]
    float* __restrict__ partials) {      // [NQ_][NSLICES_][2] = {l, acc}
  __shared__ __align__(16) short kt[64 * 128];   // 16 KB key tile
  const int t     = threadIdx.x;
  const int wave  = t >> 6;
  const int lane  = t & 63;
  const int quad  = lane >> 4;
  const int ln    = lane & 15;
  const int qbase = blockIdx.x * 256 + wave * 64;
  const int slice = blockIdx.y;
  const int tile0 = slice * TPS_;
  const int tile1 = (tile0 + TPS_ < TILES_TOT) ? (tile0 + TPS_) : TILES_TOT;

  // A fragments, register resident: a[sub][ks] covers q rows qbase+sub*16+ln
  short8v a[4][4];
#pragma unroll
  for (int sub = 0; sub < 4; ++sub)
#pragma unroll
    for (int ks = 0; ks < 4; ++ks)
      a[sub][ks] = *(const short8v*)(qb + (qbase + sub * 16 + ln) * EMB_ + ks * 32 + quad * 8);

  float lsum[4][4], asum[4][4];
#pragma unroll
  for (int i = 0; i < 4; ++i)
#pragma unroll
    for (int j = 0; j < 4; ++j) { lsum[i][j] = 0.f; asum[i][j] = 0.f; }

  // prefetch first tile into stage registers (64 B/thread)
  short8v stage[4];
  if (tile0 < tile1) {
    const short* src = keys_sw + tile0 * (64 * 128);
#pragma unroll
    for (int j = 0; j < 4; ++j)
      stage[j] = *(const short8v*)(src + (t + j * 256) * 8);
  }

  for (int tile = tile0; tile < tile1; ++tile) {
    __syncthreads();                             // previous compute done
#pragma unroll
    for (int j = 0; j < 4; ++j)                  // stage regs -> LDS (16 KB)
      *(short8v*)(kt + (t + j * 256) * 8) = stage[j];
    __syncthreads();

    if (tile + 1 < tile1) {                      // issue next tile's loads now;
      const short* nsrc = keys_sw + (tile + 1) * (64 * 128);
#pragma unroll
      for (int j = 0; j < 4; ++j)                // vmcnt stays outstanding
        stage[j] = *(const short8v*)(nsrc + (t + j * 256) * 8);
    }

#pragma unroll
    for (int nsub = 0; nsub < 4; ++nsub) {
      short8v b[4];
#pragma unroll
      for (int ks = 0; ks < 4; ++ks) {
        int kc = ks * 4 + quad;                  // logical 8-elem chunk
        b[ks] = *(const short8v*)(kt + (nsub * 16 + ln) * EMB_ + ((kc ^ ln) * 8));
      }
      float v = vpad[tile * 64 + nsub * 16 + ln];  // this lane's key-column value
#pragma unroll
      for (int sub = 0; sub < 4; ++sub) {
        float4v d = {-SHIFT_, -SHIFT_, -SHIFT_, -SHIFT_};  // softmax shift folded into C
#pragma unroll
        for (int ks = 0; ks < 4; ++ks)
          d = __builtin_amdgcn_mfma_f32_16x16x32_bf16(a[sub][ks], b[ks], d, 0, 0, 0);
#pragma unroll
        for (int r2 = 0; r2 < 4; ++r2) {
          float p = EXP2F(d[r2]);
          lsum[sub][r2] += p;
          asum[sub][r2] = fmaf(p, v, asum[sub][r2]);
        }
      }
    }
  }

  // reduce over the 16 key-column lanes (same quad); lane ln==0 writes.
  // Empty slices (61..63) still write zeros -- finalize reads all 64.
#pragma unroll
  for (int sub = 0; sub < 4; ++sub)
#pragma unroll
    for (int r2 = 0; r2 < 4; ++r2) {
      float L = lsum[sub][r2], A = asum[sub][r2];
#pragma unroll
      for (int m = 1; m < 16; m <<= 1) {
        L += __shfl_xor(L, m, 64);
        A += __shfl_xor(A, m, 64);
      }
      if (ln == 0) {
        int q = qbase + sub * 16 + quad * 4 + r2;
        partials[(q * NSLICES_ + slice) * 2 + 0] = L;
        partials[(q * NSLICES_ + slice) * 2 + 1] = A;
      }
    }
}

// ---------------------------------------------------------------------------
// Kernel 3: combine slice partials, mean over heads, add curiosity.
// One thread per (bt, head); float4 loads (per-thread data contiguous).
// ---------------------------------------------------------------------------
__global__ __launch_bounds__(256) void finalize_kernel(
    const float* __restrict__ partials, const float* __restrict__ cur,
    float* __restrict__ out) {
  int tid = blockIdx.x * 256 + threadIdx.x;      // 4096 threads
  int bt = tid >> 3, h = tid & 7;
  int q = bt * NHEADS + h;
  const float4* p = (const float4*)(partials + q * NSLICES_ * 2);
  float sl = 0.f, sa = 0.f;
#pragma unroll 8
  for (int i = 0; i < NSLICES_ / 2; ++i) {       // 2 slices per float4
    float4 v = p[i];
    sl += v.x + v.z;
    sa += v.y + v.w;
  }
  float r = sa / sl;
  r += __shfl_xor(r, 1, 64);
  r += __shfl_xor(r, 2, 64);
  r += __shfl_xor(r, 4, 64);
  if (h == 0) out[bt] = r * (1.f / NHEADS) + cur[bt];
}

// ---------------------------------------------------------------------------
extern "C" void kernel_launch(void* const* d_in, const int* in_sizes, int n_in,
                              void* d_out, int out_size, void* d_ws, size_t ws_size,
                              hipStream_t stream) {
  (void)in_sizes; (void)n_in; (void)out_size; (void)ws_size;
  const float* x      = (const float*)d_in[0];   // (4,128,1024)
  const float* cur    = (const float*)d_in[1];   // (4,128)
  const float* Wq     = (const float*)d_in[2];   // (1024,1024)
  const float* keys   = (const float*)d_in[3];   // (50000,128)
  const float* values = (const float*)d_in[4];   // (50000,)
  float* out = (float*)d_out;                    // (4,128,1) fp32

  // workspace layout (16B-aligned), ~16.2 MB total
  char* ws = (char*)d_ws;
  short* keys_sw = (short*)(ws);                        // 12,812,288 B
  float* vpad    = (float*)(ws + 12812288);             //    200,192 B
  short* qb      = (short*)(ws + 13012480);             //  1,048,576 B
  float* part    = (float*)(ws + 14061056);             //  2,097,152 B (64 slices)

  hipLaunchKernelGGL(convert_kernel, dim3((NPAD_ * 16) / 256), dim3(256), 0, stream,
                     keys, values, keys_sw, vpad);
  hipLaunchKernelGGL(proj_kernel, dim3(512), dim3(256), 0, stream, x, Wq, qb);
  hipLaunchKernelGGL(attn_kernel, dim3(16, NSLICES_), dim3(256), 0, stream,
                     qb, keys_sw, vpad, part);
  hipLaunchKernelGGL(finalize_kernel, dim3(16), dim3(256), 0, stream, part, cur, out);
}

// Round 4
// 223.403 us; speedup vs baseline: 1.3803x; 1.2854x over previous
//
#include <hip/hip_runtime.h>

// Problem constants
#define NHEADS   8
#define EMB_     128
#define BT_      512        // b*t = 4*128
#define HIN_     1024
#define NQ_      4096       // BT_*NHEADS
#define NKEY_    50000
#define NPAD_    50048      // 782 tiles of 64 keys
#define TILES_TOT 782
#define TPS_     13         // key tiles per slice
#define NSLICES_ 64         // 60 full + 1 partial (2 tiles) + 3 empty

#define CONV_BLOCKS ((NPAD_ * 16) / 256)   // 3128
#define PROJ_BLOCKS 512

// scale = 128^-0.25 (reference) * log2(e) (scores land directly in exp2 domain)
#define QSCALE   (0.29730177875068026f * 1.4426950408889634f)
#define SHIFT_   44.0f      // fixed softmax shift in log2 domain (> max score)

typedef __attribute__((ext_vector_type(8))) short short8v;   // 8 bf16 = 4 VGPRs (MFMA A/B frag)
typedef __attribute__((ext_vector_type(4))) float float4v;   // MFMA C/D frag

#if __has_builtin(__builtin_amdgcn_exp2f)
#define EXP2F(x) __builtin_amdgcn_exp2f(x)
#else
#define EXP2F(x) exp2f(x)
#endif

__device__ __forceinline__ short f2bf(float f) {  // fp32 -> bf16 bits, RNE
  unsigned u = __float_as_uint(f);
  u += 0x7fffu + ((u >> 16) & 1u);
  return (short)(u >> 16);
}

// ---------------------------------------------------------------------------
// Kernel 0 (fused prep): blocks [0, CONV_BLOCKS) convert keys fp32->bf16 with
// XOR chunk swizzle + zero-pad and pad values; blocks [CONV_BLOCKS, +512) run
// the q-projection. Branch is block-uniform (no divergence); fusing saves a
// launch. Swizzle: physical 16B chunk p of row `key` holds logical chunk
// (p ^ (key&15)) so attention's B-frag ds_read_b128 is 2-way max (free, m136).
// ---------------------------------------------------------------------------
__global__ __launch_bounds__(256) void prep_kernel(
    const float* __restrict__ keys, const float* __restrict__ values,
    short* __restrict__ keys_sw, float* __restrict__ vpad,
    const float* __restrict__ x, const float* __restrict__ Wq,
    short* __restrict__ qb) {
  if (blockIdx.x < CONV_BLOCKS) {
    // ---- keys/values conversion ----
    int idx = blockIdx.x * 256 + threadIdx.x;    // one thread per 8-elem chunk
    int key = idx >> 4;
    int p   = idx & 15;
    int lc  = p ^ (key & 15);                    // logical chunk stored here
    short8v o;
    if (key < NKEY_) {
      const float* src = keys + key * EMB_ + lc * 8;
#pragma unroll
      for (int i = 0; i < 8; ++i) o[i] = f2bf(src[i]);
    } else {
#pragma unroll
      for (int i = 0; i < 8; ++i) o[i] = 0;      // pad rows: score 0 -> p=2^-44, negligible
    }
    *(short8v*)(keys_sw + idx * 8) = o;          // coalesced 16B stores
    if (p == 0) vpad[key] = (key < NKEY_) ? values[key] : 0.f;
  } else {
    // ---- q projection: one 16x16 tile per wave, mfma_16x16x32_bf16, K=1024
    // streamed from global fp32 with inline bf16 convert (x/Wq L2-resident).
    const int wave = threadIdx.x >> 6, lane = threadIdx.x & 63;
    const int quad = lane >> 4, ln = lane & 15;
    const int tile = (blockIdx.x - CONV_BLOCKS) * 4 + wave;  // 2048 tiles
    const int mt = tile >> 6, ot = tile & 63;    // 32 m-tiles x 64 o-tiles
    const float* xrow = x  + (mt * 16 + ln) * HIN_ + quad * 8;
    const float* wrow = Wq + (ot * 16 + ln) * HIN_ + quad * 8;
    float4v d = {0.f, 0.f, 0.f, 0.f};
#pragma unroll 4
    for (int k0 = 0; k0 < HIN_; k0 += 32) {
      float4 xa = *(const float4*)(xrow + k0);
      float4 xb = *(const float4*)(xrow + k0 + 4);
      float4 wa = *(const float4*)(wrow + k0);
      float4 wb = *(const float4*)(wrow + k0 + 4);
      short8v af, bf;
      af[0]=f2bf(xa.x); af[1]=f2bf(xa.y); af[2]=f2bf(xa.z); af[3]=f2bf(xa.w);
      af[4]=f2bf(xb.x); af[5]=f2bf(xb.y); af[6]=f2bf(xb.z); af[7]=f2bf(xb.w);
      bf[0]=f2bf(wa.x); bf[1]=f2bf(wa.y); bf[2]=f2bf(wa.z); bf[3]=f2bf(wa.w);
      bf[4]=f2bf(wb.x); bf[5]=f2bf(wb.y); bf[6]=f2bf(wb.z); bf[7]=f2bf(wb.w);
      d = __builtin_amdgcn_mfma_f32_16x16x32_bf16(af, bf, d, 0, 0, 0);
    }
#pragma unroll
    for (int r2 = 0; r2 < 4; ++r2)
      qb[(mt * 16 + quad * 4 + r2) * HIN_ + ot * 16 + ln] = f2bf(d[r2] * QSCALE);
  }
}

// ---------------------------------------------------------------------------
// Kernel 1: flash-decoding attention. Grid (16 query-cols, 64 key-slices) =
// 1024 blocks. Per WG: 256 queries (4 waves x 4 sub-tiles, A-frags register-
// resident). Key tiles staged via vector loads with register prefetch.
// __launch_bounds__(256,2): rounds 2/3 showed caps of 4 (64 VGPR) and even 3
// spill loop state to scratch (WRITE_SIZE 175/290 MB); (256,2) verifiably
// allocates ~120-160 VGPR with WRITE_SIZE ~1 MB (round 1).
// ---------------------------------------------------------------------------
__global__ __launch_bounds__(256, 2) void attn_kernel(
    const short* __restrict__ qb,        // bf16 [NQ_][128]
    const short* __restrict__ keys_sw,   // bf16 [NPAD_][128], chunk-swizzled
    const float* __restrict__ vpad,      // [NPAD_]
    float* __restrict__ partials) {      // [NQ_][NSLICES_][2] = {l, acc}
  __shared__ __align__(16) short kt[64 * 128];   // 16 KB key tile
  const int t     = threadIdx.x;
  const int wave  = t >> 6;
  const int lane  = t & 63;
  const int quad  = lane >> 4;
  const int ln    = lane & 15;
  const int qbase = blockIdx.x * 256 + wave * 64;
  const int slice = blockIdx.y;
  const int tile0 = slice * TPS_;
  const int tile1 = (tile0 + TPS_ < TILES_TOT) ? (tile0 + TPS_) : TILES_TOT;

  // A fragments, register resident: a[sub][ks] covers q rows qbase+sub*16+ln
  short8v a[4][4];
#pragma unroll
  for (int sub = 0; sub < 4; ++sub)
#pragma unroll
    for (int ks = 0; ks < 4; ++ks)
      a[sub][ks] = *(const short8v*)(qb + (qbase + sub * 16 + ln) * EMB_ + ks * 32 + quad * 8);

  float lsum[4][4], asum[4][4];
#pragma unroll
  for (int i = 0; i < 4; ++i)
#pragma unroll
    for (int j = 0; j < 4; ++j) { lsum[i][j] = 0.f; asum[i][j] = 0.f; }

  // prefetch first tile into stage registers (64 B/thread)
  short8v stage[4];
  if (tile0 < tile1) {
    const short* src = keys_sw + tile0 * (64 * 128);
#pragma unroll
    for (int j = 0; j < 4; ++j)
      stage[j] = *(const short8v*)(src + (t + j * 256) * 8);
  }

  for (int tile = tile0; tile < tile1; ++tile) {
    __syncthreads();                             // previous compute done
#pragma unroll
    for (int j = 0; j < 4; ++j)                  // stage regs -> LDS (16 KB)
      *(short8v*)(kt + (t + j * 256) * 8) = stage[j];
    __syncthreads();

    if (tile + 1 < tile1) {                      // issue next tile's loads now;
      const short* nsrc = keys_sw + (tile + 1) * (64 * 128);
#pragma unroll
      for (int j = 0; j < 4; ++j)                // vmcnt stays outstanding
        stage[j] = *(const short8v*)(nsrc + (t + j * 256) * 8);
    }

#pragma unroll
    for (int nsub = 0; nsub < 4; ++nsub) {
      short8v b[4];
#pragma unroll
      for (int ks = 0; ks < 4; ++ks) {
        int kc = ks * 4 + quad;                  // logical 8-elem chunk
        b[ks] = *(const short8v*)(kt + (nsub * 16 + ln) * EMB_ + ((kc ^ ln) * 8));
      }
      float v = vpad[tile * 64 + nsub * 16 + ln];  // this lane's key-column value
#pragma unroll
      for (int sub = 0; sub < 4; ++sub) {
        float4v d = {-SHIFT_, -SHIFT_, -SHIFT_, -SHIFT_};  // softmax shift folded into C
#pragma unroll
        for (int ks = 0; ks < 4; ++ks)
          d = __builtin_amdgcn_mfma_f32_16x16x32_bf16(a[sub][ks], b[ks], d, 0, 0, 0);
#pragma unroll
        for (int r2 = 0; r2 < 4; ++r2) {
          float p = EXP2F(d[r2]);
          lsum[sub][r2] += p;
          asum[sub][r2] = fmaf(p, v, asum[sub][r2]);
        }
      }
    }
  }

  // reduce over the 16 key-column lanes (same quad); lane ln==0 writes.
  // Empty slices (61..63) still write zeros -- finalize reads all 64.
#pragma unroll
  for (int sub = 0; sub < 4; ++sub)
#pragma unroll
    for (int r2 = 0; r2 < 4; ++r2) {
      float L = lsum[sub][r2], A = asum[sub][r2];
#pragma unroll
      for (int m = 1; m < 16; m <<= 1) {
        L += __shfl_xor(L, m, 64);
        A += __shfl_xor(A, m, 64);
      }
      if (ln == 0) {
        int q = qbase + sub * 16 + quad * 4 + r2;
        partials[(q * NSLICES_ + slice) * 2 + 0] = L;
        partials[(q * NSLICES_ + slice) * 2 + 1] = A;
      }
    }
}

// ---------------------------------------------------------------------------
// Kernel 2: combine slice partials, mean over heads, add curiosity.
// One thread per (bt, head); float4 loads (per-thread data contiguous).
// ---------------------------------------------------------------------------
__global__ __launch_bounds__(256) void finalize_kernel(
    const float* __restrict__ partials, const float* __restrict__ cur,
    float* __restrict__ out) {
  int tid = blockIdx.x * 256 + threadIdx.x;      // 4096 threads
  int bt = tid >> 3, h = tid & 7;
  int q = bt * NHEADS + h;
  const float4* p = (const float4*)(partials + q * NSLICES_ * 2);
  float sl = 0.f, sa = 0.f;
#pragma unroll 8
  for (int i = 0; i < NSLICES_ / 2; ++i) {       // 2 slices per float4
    float4 v = p[i];
    sl += v.x + v.z;
    sa += v.y + v.w;
  }
  float r = sa / sl;
  r += __shfl_xor(r, 1, 64);
  r += __shfl_xor(r, 2, 64);
  r += __shfl_xor(r, 4, 64);
  if (h == 0) out[bt] = r * (1.f / NHEADS) + cur[bt];
}

// ---------------------------------------------------------------------------
extern "C" void kernel_launch(void* const* d_in, const int* in_sizes, int n_in,
                              void* d_out, int out_size, void* d_ws, size_t ws_size,
                              hipStream_t stream) {
  (void)in_sizes; (void)n_in; (void)out_size; (void)ws_size;
  const float* x      = (const float*)d_in[0];   // (4,128,1024)
  const float* cur    = (const float*)d_in[1];   // (4,128)
  const float* Wq     = (const float*)d_in[2];   // (1024,1024)
  const float* keys   = (const float*)d_in[3];   // (50000,128)
  const float* values = (const float*)d_in[4];   // (50000,)
  float* out = (float*)d_out;                    // (4,128,1) fp32

  // workspace layout (16B-aligned), ~16.2 MB total
  char* ws = (char*)d_ws;
  short* keys_sw = (short*)(ws);                        // 12,812,288 B
  float* vpad    = (float*)(ws + 12812288);             //    200,192 B
  short* qb      = (short*)(ws + 13012480);             //  1,048,576 B
  float* part    = (float*)(ws + 14061056);             //  2,097,152 B (64 slices)

  hipLaunchKernelGGL(prep_kernel, dim3(CONV_BLOCKS + PROJ_BLOCKS), dim3(256), 0, stream,
                     keys, values, keys_sw, vpad, x, Wq, qb);
  hipLaunchKernelGGL(attn_kernel, dim3(16, NSLICES_), dim3(256), 0, stream,
                     qb, keys_sw, vpad, part);
  hipLaunchKernelGGL(finalize_kernel, dim3(16), dim3(256), 0, stream, part, cur, out);
}

// Round 5
// 184.105 us; speedup vs baseline: 1.6749x; 1.2135x over previous
//
#include <hip/hip_runtime.h>

// Problem constants
#define NHEADS   8
#define EMB_     128
#define BT_      512        // b*t = 4*128
#define HIN_     1024
#define NQ_      4096       // BT_*NHEADS
#define NKEY_    50000
#define NPAD_    50048      // 782 tiles of 64 keys
#define TILES_TOT 782
#define TPS_     17         // key tiles per slice: 46*17 = 782 exactly
#define NSLICES_ 46         // grid 16x46 = 736 blocks -> one pass at 3 blk/CU

// scale = 128^-0.25 (reference) * log2(e) (scores land directly in exp2 domain)
#define QSCALE   (0.29730177875068026f * 1.4426950408889634f)
#define SHIFT_   44.0f      // fixed softmax shift in log2 domain (> max score)

typedef __attribute__((ext_vector_type(8))) short short8v;   // 8 bf16 = 4 VGPRs (MFMA A/B frag)
typedef __attribute__((ext_vector_type(4))) float float4v;   // MFMA C/D frag

#if __has_builtin(__builtin_amdgcn_exp2f)
#define EXP2F(x) __builtin_amdgcn_exp2f(x)
#else
#define EXP2F(x) exp2f(x)
#endif

__device__ __forceinline__ short f2bf(float f) {  // fp32 -> bf16 bits, RNE
  unsigned u = __float_as_uint(f);
  u += 0x7fffu + ((u >> 16) & 1u);
  return (short)(u >> 16);
}

// ---------------------------------------------------------------------------
// Kernel 0: keys fp32 -> bf16 with XOR chunk swizzle + zero-pad; values padded.
// Physical 16B chunk p of row `key` holds logical chunk (p ^ (key&15)) so the
// attention B-frag ds_read_b128 is 2-way max (free, m136) with NO padding.
// (Standalone: round-4 fusion let the allocator size the whole kernel for
// this branch -> 24 VGPR -> serialized proj. Never fuse unlike branches.)
// ---------------------------------------------------------------------------
__global__ __launch_bounds__(256) void convert_kernel(
    const float* __restrict__ keys, const float* __restrict__ values,
    short* __restrict__ keys_sw, float* __restrict__ vpad) {
  int idx = blockIdx.x * 256 + threadIdx.x;      // one thread per 8-elem chunk
  if (idx >= NPAD_ * 16) return;
  int key = idx >> 4;
  int p   = idx & 15;
  int lc  = p ^ (key & 15);                      // logical chunk stored here
  short8v o;
  if (key < NKEY_) {
    const float* src = keys + key * EMB_ + lc * 8;
#pragma unroll
    for (int i = 0; i < 8; ++i) o[i] = f2bf(src[i]);
  } else {
#pragma unroll
    for (int i = 0; i < 8; ++i) o[i] = 0;        // pad rows: score 0 -> p=2^-44, negligible
  }
  *(short8v*)(keys_sw + idx * 8) = o;            // coalesced 16B stores
  if (p == 0) vpad[key] = (key < NKEY_) ? values[key] : 0.f;
}

// ---------------------------------------------------------------------------
// Kernel 1: q = (x @ Wq^T) * QSCALE -> bf16. One 16x16 tile per wave via
// mfma_16x16x32_bf16. EXPLICIT 2-stage register pipeline: loads for k-chunk
// i+2 are issued while chunk i computes -> 8 dwordx4 always in flight, L2
// latency (~300cy) covered by ~2 iterations of convert+MFMA work.
// __launch_bounds__(256,1): empirically (r1-r4) arg n caps VGPR at ~512/2n;
// n=1 -> 256-reg budget, no starvation, no spill. Occupancy is irrelevant
// here (512 blocks = 2/CU either way).
// ---------------------------------------------------------------------------
__global__ __launch_bounds__(256, 1) void proj_kernel(
    const float* __restrict__ x, const float* __restrict__ Wq,
    short* __restrict__ qb) {
  const int wave = threadIdx.x >> 6, lane = threadIdx.x & 63;
  const int quad = lane >> 4, ln = lane & 15;
  const int tile = blockIdx.x * 4 + wave;        // 2048 tiles
  const int mt = tile >> 6, ot = tile & 63;      // 32 m-tiles x 64 o-tiles
  const float* xrow = x  + (mt * 16 + ln) * HIN_ + quad * 8;
  const float* wrow = Wq + (ot * 16 + ln) * HIN_ + quad * 8;
  float4v d = {0.f, 0.f, 0.f, 0.f};

  float4 xc[2][2], wc[2][2];                     // [stage][half], 32 VGPRs
#pragma unroll
  for (int s = 0; s < 2; ++s) {
    xc[s][0] = *(const float4*)(xrow + s * 32);
    xc[s][1] = *(const float4*)(xrow + s * 32 + 4);
    wc[s][0] = *(const float4*)(wrow + s * 32);
    wc[s][1] = *(const float4*)(wrow + s * 32 + 4);
  }
#pragma unroll
  for (int it = 0; it < 32; ++it) {              // k-chunk = 32 floats
    const int s = it & 1;
    float4 xa = xc[s][0], xb = xc[s][1];
    float4 wa = wc[s][0], wb = wc[s][1];
    const int kn = (it + 2) * 32;
    if (kn < HIN_) {                             // issue next-next chunk now
      xc[s][0] = *(const float4*)(xrow + kn);
      xc[s][1] = *(const float4*)(xrow + kn + 4);
      wc[s][0] = *(const float4*)(wrow + kn);
      wc[s][1] = *(const float4*)(wrow + kn + 4);
    }
    short8v af, bf;
    af[0]=f2bf(xa.x); af[1]=f2bf(xa.y); af[2]=f2bf(xa.z); af[3]=f2bf(xa.w);
    af[4]=f2bf(xb.x); af[5]=f2bf(xb.y); af[6]=f2bf(xb.z); af[7]=f2bf(xb.w);
    bf[0]=f2bf(wa.x); bf[1]=f2bf(wa.y); bf[2]=f2bf(wa.z); bf[3]=f2bf(wa.w);
    bf[4]=f2bf(wb.x); bf[5]=f2bf(wb.y); bf[6]=f2bf(wb.z); bf[7]=f2bf(wb.w);
    d = __builtin_amdgcn_mfma_f32_16x16x32_bf16(af, bf, d, 0, 0, 0);
  }
#pragma unroll
  for (int r2 = 0; r2 < 4; ++r2)
    qb[(mt * 16 + quad * 4 + r2) * HIN_ + ot * 16 + ln] = f2bf(d[r2] * QSCALE);
}

// ---------------------------------------------------------------------------
// Kernel 2: flash-decoding attention. Grid (16 query-cols, 46 key-slices) =
// 736 blocks, all slices full (17 tiles). Ping-pong LDS: ONE barrier per
// tile. Iteration order: (1) write prefetched tile+1 into idle buffer,
// (2) issue global loads for tile+2, (3) compute tile from current buffer,
// (4) barrier (its vmcnt(0) drain lands after ~1.5k cy of compute).
// No min-waves bound: rounds 2/3 proved caps of 64/84 VGPR spill the loop
// state to scratch (175/290 MB writes). Expect ~140-160 VGPR -> 3 blk/CU.
// ---------------------------------------------------------------------------
__global__ __launch_bounds__(256) void attn_kernel(
    const short* __restrict__ qb,        // bf16 [NQ_][128]
    const short* __restrict__ keys_sw,   // bf16 [NPAD_][128], chunk-swizzled
    const float* __restrict__ vpad,      // [NPAD_]
    float* __restrict__ partials) {      // [NQ_][NSLICES_][2] = {l, acc}
  __shared__ __align__(16) short kt[2][64 * 128];   // 2 x 16 KB ping-pong
  const int t     = threadIdx.x;
  const int wave  = t >> 6;
  const int lane  = t & 63;
  const int quad  = lane >> 4;
  const int ln    = lane & 15;
  const int qbase = blockIdx.x * 256 + wave * 64;
  const int slice = blockIdx.y;
  const int tile0 = slice * TPS_;
  const int tile1 = tile0 + TPS_;                // all slices full (46*17=782)

  // A fragments, register resident: a[sub][ks] covers q rows qbase+sub*16+ln
  short8v a[4][4];
#pragma unroll
  for (int sub = 0; sub < 4; ++sub)
#pragma unroll
    for (int ks = 0; ks < 4; ++ks)
      a[sub][ks] = *(const short8v*)(qb + (qbase + sub * 16 + ln) * EMB_ + ks * 32 + quad * 8);

  float lsum[4][4], asum[4][4];
#pragma unroll
  for (int i = 0; i < 4; ++i)
#pragma unroll
    for (int j = 0; j < 4; ++j) { lsum[i][j] = 0.f; asum[i][j] = 0.f; }

  short8v stage[4];                              // 64 B/thread prefetch window
  {                                              // preload tile0 -> buf0
    const short* src = keys_sw + tile0 * (64 * 128);
#pragma unroll
    for (int j = 0; j < 4; ++j)
      stage[j] = *(const short8v*)(src + (t + j * 256) * 8);
#pragma unroll
    for (int j = 0; j < 4; ++j)
      *(short8v*)(&kt[0][0] + (t + j * 256) * 8) = stage[j];
    const short* s1 = keys_sw + (tile0 + 1) * (64 * 128);  // prefetch tile0+1
#pragma unroll
    for (int j = 0; j < 4; ++j)
      stage[j] = *(const short8v*)(s1 + (t + j * 256) * 8);
  }
  __syncthreads();

  for (int tile = tile0; tile < tile1; ++tile) {
    const int cur = (tile - tile0) & 1;
    // (1) park prefetched tile+1 in the idle buffer (its readers synced last iter)
    if (tile + 1 < tile1) {
#pragma unroll
      for (int j = 0; j < 4; ++j)
        *(short8v*)(&kt[cur ^ 1][0] + (t + j * 256) * 8) = stage[j];
    }
    // (2) issue tile+2 global loads now; latency hides under (3)
    if (tile + 2 < tile1) {
      const short* nsrc = keys_sw + (tile + 2) * (64 * 128);
#pragma unroll
      for (int j = 0; j < 4; ++j)
        stage[j] = *(const short8v*)(nsrc + (t + j * 256) * 8);
    }
    // (3) compute this tile from kt[cur]
#pragma unroll
    for (int nsub = 0; nsub < 4; ++nsub) {
      short8v b[4];
#pragma unroll
      for (int ks = 0; ks < 4; ++ks) {
        int kc = ks * 4 + quad;                  // logical 8-elem chunk
        b[ks] = *(const short8v*)(&kt[cur][0] + (nsub * 16 + ln) * EMB_ + ((kc ^ ln) * 8));
      }
      float v = vpad[tile * 64 + nsub * 16 + ln];  // this lane's key-column value
#pragma unroll
      for (int sub = 0; sub < 4; ++sub) {
        float4v d = {-SHIFT_, -SHIFT_, -SHIFT_, -SHIFT_};  // softmax shift folded into C
#pragma unroll
        for (int ks = 0; ks < 4; ++ks)
          d = __builtin_amdgcn_mfma_f32_16x16x32_bf16(a[sub][ks], b[ks], d, 0, 0, 0);
#pragma unroll
        for (int r2 = 0; r2 < 4; ++r2) {
          float p = EXP2F(d[r2]);
          lsum[sub][r2] += p;
          asum[sub][r2] = fmaf(p, v, asum[sub][r2]);
        }
      }
    }
    // (4) single barrier: tile+1 writes visible, tile's reads retired
    __syncthreads();
  }

  // reduce over the 16 key-column lanes (same quad); lane ln==0 writes
#pragma unroll
  for (int sub = 0; sub < 4; ++sub)
#pragma unroll
    for (int r2 = 0; r2 < 4; ++r2) {
      float L = lsum[sub][r2], A = asum[sub][r2];
#pragma unroll
      for (int m = 1; m < 16; m <<= 1) {
        L += __shfl_xor(L, m, 64);
        A += __shfl_xor(A, m, 64);
      }
      if (ln == 0) {
        int q = qbase + sub * 16 + quad * 4 + r2;
        partials[(q * NSLICES_ + slice) * 2 + 0] = L;
        partials[(q * NSLICES_ + slice) * 2 + 1] = A;
      }
    }
}

// ---------------------------------------------------------------------------
// Kernel 3: combine slice partials, mean over heads, add curiosity.
// One thread per (bt, head); 46 slices * 2 floats = 23 float4 loads.
// ---------------------------------------------------------------------------
__global__ __launch_bounds__(256) void finalize_kernel(
    const float* __restrict__ partials, const float* __restrict__ cur,
    float* __restrict__ out) {
  int tid = blockIdx.x * 256 + threadIdx.x;      // 4096 threads
  int bt = tid >> 3, h = tid & 7;
  int q = bt * NHEADS + h;
  const float4* p = (const float4*)(partials + q * NSLICES_ * 2);
  float sl = 0.f, sa = 0.f;
#pragma unroll
  for (int i = 0; i < NSLICES_ / 2; ++i) {       // 2 slices per float4
    float4 v = p[i];
    sl += v.x + v.z;
    sa += v.y + v.w;
  }
  float r = sa / sl;
  r += __shfl_xor(r, 1, 64);
  r += __shfl_xor(r, 2, 64);
  r += __shfl_xor(r, 4, 64);
  if (h == 0) out[bt] = r * (1.f / NHEADS) + cur[bt];
}

// ---------------------------------------------------------------------------
extern "C" void kernel_launch(void* const* d_in, const int* in_sizes, int n_in,
                              void* d_out, int out_size, void* d_ws, size_t ws_size,
                              hipStream_t stream) {
  (void)in_sizes; (void)n_in; (void)out_size; (void)ws_size;
  const float* x      = (const float*)d_in[0];   // (4,128,1024)
  const float* cur    = (const float*)d_in[1];   // (4,128)
  const float* Wq     = (const float*)d_in[2];   // (1024,1024)
  const float* keys   = (const float*)d_in[3];   // (50000,128)
  const float* values = (const float*)d_in[4];   // (50000,)
  float* out = (float*)d_out;                    // (4,128,1) fp32

  // workspace layout (16B-aligned), ~15.6 MB total
  char* ws = (char*)d_ws;
  short* keys_sw = (short*)(ws);                        // 12,812,288 B
  float* vpad    = (float*)(ws + 12812288);             //    200,192 B
  short* qb      = (short*)(ws + 13012480);             //  1,048,576 B
  float* part    = (float*)(ws + 14061056);             //  1,507,328 B (46 slices)

  hipLaunchKernelGGL(convert_kernel, dim3((NPAD_ * 16) / 256), dim3(256), 0, stream,
                     keys, values, keys_sw, vpad);
  hipLaunchKernelGGL(proj_kernel, dim3(512), dim3(256), 0, stream, x, Wq, qb);
  hipLaunchKernelGGL(attn_kernel, dim3(16, NSLICES_), dim3(256), 0, stream,
                     qb, keys_sw, vpad, part);
  hipLaunchKernelGGL(finalize_kernel, dim3(16), dim3(256), 0, stream, part, cur, out);
}

// Round 6
// 180.685 us; speedup vs baseline: 1.7066x; 1.0189x over previous
//
#include <hip/hip_runtime.h>

// Problem constants
#define NHEADS   8
#define EMB_     128
#define BT_      512        // b*t = 4*128
#define HIN_     1024
#define NQ_      4096       // BT_*NHEADS
#define NKEY_    50000
#define NPAD_    50048      // 782 tiles of 64 keys
#define TILES_TOT 782
#define TPS_     17         // key tiles per slice: 46*17 = 782 exactly
#define NSLICES_ 46         // grid 16x46 = 736 blocks

// scale = 128^-0.25 (reference) * log2(e) (scores land directly in exp2 domain)
#define QSCALE   (0.29730177875068026f * 1.4426950408889634f)
#define SHIFT_   44.0f      // fixed softmax shift in log2 domain (> max score)

typedef __attribute__((ext_vector_type(8))) short short8v;   // 8 bf16 = 4 VGPRs (MFMA A/B frag)
typedef __attribute__((ext_vector_type(4))) float float4v;   // MFMA C/D frag

#if __has_builtin(__builtin_amdgcn_exp2f)
#define EXP2F(x) __builtin_amdgcn_exp2f(x)
#else
#define EXP2F(x) exp2f(x)
#endif

__device__ __forceinline__ short f2bf(float f) {  // fp32 -> bf16 bits, RNE
  unsigned u = __float_as_uint(f);
  u += 0x7fffu + ((u >> 16) & 1u);
  return (short)(u >> 16);
}

// packed fp32x2 -> bf16x2 (gfx950 v_cvt_pk_bf16_f32 when available)
#if __has_builtin(__builtin_amdgcn_cvt_pk_bf16_f32)
typedef __attribute__((ext_vector_type(2))) __bf16 bf16x2;
__device__ __forceinline__ unsigned pk2(float a, float b) {
  bf16x2 r = __builtin_amdgcn_cvt_pk_bf16_f32(a, b);
  union { bf16x2 v; unsigned u; } c; c.v = r; return c.u;
}
#else
__device__ __forceinline__ unsigned pk2(float a, float b) {
  return (unsigned)(unsigned short)f2bf(a) | ((unsigned)(unsigned short)f2bf(b) << 16);
}
#endif

// ---------------------------------------------------------------------------
// Kernel 0: keys fp32 -> bf16, XOR chunk swizzle applied ON THE STORE SIDE.
// XOR is an involution, so storing logical chunk lc at physical lc^(key&15)
// is identical to round-5's layout -- but loads are now two dense float4
// (wave = 4 KB contiguous) instead of 8 scalar dwords spanning 32 cache
// lines at stride 32 B (the round-1..5 convert was ~68 us, latency-bound on
// line-split scalar loads; residue arithmetic r1 vs r4). Stores are 16 B
// chunks permuted within a 256 B row -- wave still covers contiguous 1 KB.
// ---------------------------------------------------------------------------
__global__ __launch_bounds__(256) void convert_kernel(
    const float* __restrict__ keys, const float* __restrict__ values,
    short* __restrict__ keys_sw, float* __restrict__ vpad) {
  int idx = blockIdx.x * 256 + threadIdx.x;      // logical 8-elem chunk id
  int key = idx >> 4;
  int lc  = idx & 15;                            // logical chunk (LINEAR loads)
  union { short8v s; unsigned u[4]; } o;
  if (key < NKEY_) {
    const float4* src = (const float4*)(keys + key * EMB_ + lc * 8);
    float4 v0 = src[0], v1 = src[1];
    o.u[0] = pk2(v0.x, v0.y); o.u[1] = pk2(v0.z, v0.w);
    o.u[2] = pk2(v1.x, v1.y); o.u[3] = pk2(v1.z, v1.w);
  } else {
    o.u[0] = 0; o.u[1] = 0; o.u[2] = 0; o.u[3] = 0;  // pad rows -> p=2^-44
  }
  int pc = lc ^ (key & 15);                      // physical chunk (swizzle on store)
  *(short8v*)(keys_sw + (key * 16 + pc) * 8) = o.s;
  if (lc == 0) vpad[key] = (key < NKEY_) ? values[key] : 0.f;
}

// ---------------------------------------------------------------------------
// Kernel 1: q = (x @ Wq^T) * QSCALE -> bf16. One 16x16 tile per wave via
// mfma_16x16x32_bf16, 2-stage register pipeline (loads for chunk i+2 in
// flight while chunk i computes). Packed cvt_pk_bf16_f32 halves the
// convert VALU chain. __launch_bounds__(256,1): full register budget
// (r2/r3 lesson: tighter caps spill loop state to scratch).
// ---------------------------------------------------------------------------
__global__ __launch_bounds__(256, 1) void proj_kernel(
    const float* __restrict__ x, const float* __restrict__ Wq,
    short* __restrict__ qb) {
  const int wave = threadIdx.x >> 6, lane = threadIdx.x & 63;
  const int quad = lane >> 4, ln = lane & 15;
  const int tile = blockIdx.x * 4 + wave;        // 2048 tiles
  const int mt = tile >> 6, ot = tile & 63;      // 32 m-tiles x 64 o-tiles
  const float* xrow = x  + (mt * 16 + ln) * HIN_ + quad * 8;
  const float* wrow = Wq + (ot * 16 + ln) * HIN_ + quad * 8;
  float4v d = {0.f, 0.f, 0.f, 0.f};

  float4 xc[2][2], wc[2][2];                     // [stage][half], 32 VGPRs
#pragma unroll
  for (int s = 0; s < 2; ++s) {
    xc[s][0] = *(const float4*)(xrow + s * 32);
    xc[s][1] = *(const float4*)(xrow + s * 32 + 4);
    wc[s][0] = *(const float4*)(wrow + s * 32);
    wc[s][1] = *(const float4*)(wrow + s * 32 + 4);
  }
#pragma unroll
  for (int it = 0; it < 32; ++it) {              // k-chunk = 32 floats
    const int s = it & 1;
    float4 xa = xc[s][0], xb = xc[s][1];
    float4 wa = wc[s][0], wb = wc[s][1];
    const int kn = (it + 2) * 32;
    if (kn < HIN_) {                             // issue next-next chunk now
      xc[s][0] = *(const float4*)(xrow + kn);
      xc[s][1] = *(const float4*)(xrow + kn + 4);
      wc[s][0] = *(const float4*)(wrow + kn);
      wc[s][1] = *(const float4*)(wrow + kn + 4);
    }
    union { short8v s8; unsigned u[4]; } af, bf;
    af.u[0] = pk2(xa.x, xa.y); af.u[1] = pk2(xa.z, xa.w);
    af.u[2] = pk2(xb.x, xb.y); af.u[3] = pk2(xb.z, xb.w);
    bf.u[0] = pk2(wa.x, wa.y); bf.u[1] = pk2(wa.z, wa.w);
    bf.u[2] = pk2(wb.x, wb.y); bf.u[3] = pk2(wb.z, wb.w);
    d = __builtin_amdgcn_mfma_f32_16x16x32_bf16(af.s8, bf.s8, d, 0, 0, 0);
  }
#pragma unroll
  for (int r2 = 0; r2 < 4; ++r2)
    qb[(mt * 16 + quad * 4 + r2) * HIN_ + ot * 16 + ln] = f2bf(d[r2] * QSCALE);
}

// ---------------------------------------------------------------------------
// Kernel 2: flash-decoding attention -- UNCHANGED from round 5 (76 us, no
// spill, 0 bank conflicts) for clean residue attribution of the convert fix.
// ---------------------------------------------------------------------------
__global__ __launch_bounds__(256) void attn_kernel(
    const short* __restrict__ qb,        // bf16 [NQ_][128]
    const short* __restrict__ keys_sw,   // bf16 [NPAD_][128], chunk-swizzled
    const float* __restrict__ vpad,      // [NPAD_]
    float* __restrict__ partials) {      // [NQ_][NSLICES_][2] = {l, acc}
  __shared__ __align__(16) short kt[2][64 * 128];   // 2 x 16 KB ping-pong
  const int t     = threadIdx.x;
  const int wave  = t >> 6;
  const int lane  = t & 63;
  const int quad  = lane >> 4;
  const int ln    = lane & 15;
  const int qbase = blockIdx.x * 256 + wave * 64;
  const int slice = blockIdx.y;
  const int tile0 = slice * TPS_;
  const int tile1 = tile0 + TPS_;                // all slices full (46*17=782)

  short8v a[4][4];
#pragma unroll
  for (int sub = 0; sub < 4; ++sub)
#pragma unroll
    for (int ks = 0; ks < 4; ++ks)
      a[sub][ks] = *(const short8v*)(qb + (qbase + sub * 16 + ln) * EMB_ + ks * 32 + quad * 8);

  float lsum[4][4], asum[4][4];
#pragma unroll
  for (int i = 0; i < 4; ++i)
#pragma unroll
    for (int j = 0; j < 4; ++j) { lsum[i][j] = 0.f; asum[i][j] = 0.f; }

  short8v stage[4];                              // 64 B/thread prefetch window
  {                                              // preload tile0 -> buf0
    const short* src = keys_sw + tile0 * (64 * 128);
#pragma unroll
    for (int j = 0; j < 4; ++j)
      stage[j] = *(const short8v*)(src + (t + j * 256) * 8);
#pragma unroll
    for (int j = 0; j < 4; ++j)
      *(short8v*)(&kt[0][0] + (t + j * 256) * 8) = stage[j];
    const short* s1 = keys_sw + (tile0 + 1) * (64 * 128);  // prefetch tile0+1
#pragma unroll
    for (int j = 0; j < 4; ++j)
      stage[j] = *(const short8v*)(s1 + (t + j * 256) * 8);
  }
  __syncthreads();

  for (int tile = tile0; tile < tile1; ++tile) {
    const int cur = (tile - tile0) & 1;
    if (tile + 1 < tile1) {                      // park prefetched tile+1
#pragma unroll
      for (int j = 0; j < 4; ++j)
        *(short8v*)(&kt[cur ^ 1][0] + (t + j * 256) * 8) = stage[j];
    }
    if (tile + 2 < tile1) {                      // issue tile+2 loads now
      const short* nsrc = keys_sw + (tile + 2) * (64 * 128);
#pragma unroll
      for (int j = 0; j < 4; ++j)
        stage[j] = *(const short8v*)(nsrc + (t + j * 256) * 8);
    }
#pragma unroll
    for (int nsub = 0; nsub < 4; ++nsub) {
      short8v b[4];
#pragma unroll
      for (int ks = 0; ks < 4; ++ks) {
        int kc = ks * 4 + quad;                  // logical 8-elem chunk
        b[ks] = *(const short8v*)(&kt[cur][0] + (nsub * 16 + ln) * EMB_ + ((kc ^ ln) * 8));
      }
      float v = vpad[tile * 64 + nsub * 16 + ln];
#pragma unroll
      for (int sub = 0; sub < 4; ++sub) {
        float4v d = {-SHIFT_, -SHIFT_, -SHIFT_, -SHIFT_};
#pragma unroll
        for (int ks = 0; ks < 4; ++ks)
          d = __builtin_amdgcn_mfma_f32_16x16x32_bf16(a[sub][ks], b[ks], d, 0, 0, 0);
#pragma unroll
        for (int r2 = 0; r2 < 4; ++r2) {
          float p = EXP2F(d[r2]);
          lsum[sub][r2] += p;
          asum[sub][r2] = fmaf(p, v, asum[sub][r2]);
        }
      }
    }
    __syncthreads();
  }

#pragma unroll
  for (int sub = 0; sub < 4; ++sub)
#pragma unroll
    for (int r2 = 0; r2 < 4; ++r2) {
      float L = lsum[sub][r2], A = asum[sub][r2];
#pragma unroll
      for (int m = 1; m < 16; m <<= 1) {
        L += __shfl_xor(L, m, 64);
        A += __shfl_xor(A, m, 64);
      }
      if (ln == 0) {
        int q = qbase + sub * 16 + quad * 4 + r2;
        partials[(q * NSLICES_ + slice) * 2 + 0] = L;
        partials[(q * NSLICES_ + slice) * 2 + 1] = A;
      }
    }
}

// ---------------------------------------------------------------------------
// Kernel 3: combine slice partials, mean over heads, add curiosity.
// ---------------------------------------------------------------------------
__global__ __launch_bounds__(256) void finalize_kernel(
    const float* __restrict__ partials, const float* __restrict__ cur,
    float* __restrict__ out) {
  int tid = blockIdx.x * 256 + threadIdx.x;      // 4096 threads
  int bt = tid >> 3, h = tid & 7;
  int q = bt * NHEADS + h;
  const float4* p = (const float4*)(partials + q * NSLICES_ * 2);
  float sl = 0.f, sa = 0.f;
#pragma unroll
  for (int i = 0; i < NSLICES_ / 2; ++i) {       // 2 slices per float4
    float4 v = p[i];
    sl += v.x + v.z;
    sa += v.y + v.w;
  }
  float r = sa / sl;
  r += __shfl_xor(r, 1, 64);
  r += __shfl_xor(r, 2, 64);
  r += __shfl_xor(r, 4, 64);
  if (h == 0) out[bt] = r * (1.f / NHEADS) + cur[bt];
}

// ---------------------------------------------------------------------------
extern "C" void kernel_launch(void* const* d_in, const int* in_sizes, int n_in,
                              void* d_out, int out_size, void* d_ws, size_t ws_size,
                              hipStream_t stream) {
  (void)in_sizes; (void)n_in; (void)out_size; (void)ws_size;
  const float* x      = (const float*)d_in[0];   // (4,128,1024)
  const float* cur    = (const float*)d_in[1];   // (4,128)
  const float* Wq     = (const float*)d_in[2];   // (1024,1024)
  const float* keys   = (const float*)d_in[3];   // (50000,128)
  const float* values = (const float*)d_in[4];   // (50000,)
  float* out = (float*)d_out;                    // (4,128,1) fp32

  // workspace layout (16B-aligned), ~15.6 MB total
  char* ws = (char*)d_ws;
  short* keys_sw = (short*)(ws);                        // 12,812,288 B
  float* vpad    = (float*)(ws + 12812288);             //    200,192 B
  short* qb      = (short*)(ws + 13012480);             //  1,048,576 B
  float* part    = (float*)(ws + 14061056);             //  1,507,328 B (46 slices)

  hipLaunchKernelGGL(convert_kernel, dim3((NPAD_ * 16) / 256), dim3(256), 0, stream,
                     keys, values, keys_sw, vpad);
  hipLaunchKernelGGL(proj_kernel, dim3(512), dim3(256), 0, stream, x, Wq, qb);
  hipLaunchKernelGGL(attn_kernel, dim3(16, NSLICES_), dim3(256), 0, stream,
                     qb, keys_sw, vpad, part);
  hipLaunchKernelGGL(finalize_kernel, dim3(16), dim3(256), 0, stream, part, cur, out);
}

// Round 7
// 180.041 us; speedup vs baseline: 1.7127x; 1.0036x over previous
//
#include <hip/hip_runtime.h>

// Problem constants
#define NHEADS   8
#define EMB_     128
#define BT_      512        // b*t = 4*128
#define HIN_     1024
#define NQ_      4096       // BT_*NHEADS
#define NKEY_    50000
#define NPAD_    50048      // 782 tiles of 64 keys
#define TILES_TOT 782
#define TPS_     13         // key tiles per slice
#define NSLICES_ 61         // 60 full + 1 slice of 2 tiles; grid 16x61=976 blk

#define PROJ_BLOCKS 512
#define CONV_BLOCKS ((NPAD_ * 16) / 256)   // 3128

// scale = 128^-0.25 (reference) * log2(e) (scores land directly in exp2 domain)
#define QSCALE   (0.29730177875068026f * 1.4426950408889634f)
#define SHIFT_   44.0f      // fixed softmax shift in log2 domain (> max score)

typedef __attribute__((ext_vector_type(8))) short short8v;   // 8 bf16 = 4 VGPRs (MFMA A/B frag)
typedef __attribute__((ext_vector_type(4))) float float4v;   // MFMA C/D frag

#if __has_builtin(__builtin_amdgcn_exp2f)
#define EXP2F(x) __builtin_amdgcn_exp2f(x)
#else
#define EXP2F(x) exp2f(x)
#endif

__device__ __forceinline__ short f2bf(float f) {  // fp32 -> bf16 bits, RNE
  unsigned u = __float_as_uint(f);
  u += 0x7fffu + ((u >> 16) & 1u);
  return (short)(u >> 16);
}

// packed fp32x2 -> bf16x2 (gfx950 v_cvt_pk_bf16_f32 when available)
#if __has_builtin(__builtin_amdgcn_cvt_pk_bf16_f32)
typedef __attribute__((ext_vector_type(2))) __bf16 bf16x2;
__device__ __forceinline__ unsigned pk2(float a, float b) {
  bf16x2 r = __builtin_amdgcn_cvt_pk_bf16_f32(a, b);
  union { bf16x2 v; unsigned u; } c; c.v = r; return c.u;
}
#else
__device__ __forceinline__ unsigned pk2(float a, float b) {
  return (unsigned)(unsigned short)f2bf(a) | ((unsigned)(unsigned short)f2bf(b) << 16);
}
#endif

// ---------------------------------------------------------------------------
// Kernel 0 (fused prep): blocks [0, PROJ_BLOCKS) do the q-projection; blocks
// [PROJ_BLOCKS, +CONV_BLOCKS) convert keys->bf16 (store-side XOR swizzle).
// The halves are DATA-INDEPENDENT, so their blocks co-execute: proj's
// latency-bound waves overlap convert's BW streaming, and one launch gap
// disappears (r6 residue: ~85 us of non-kernel time across 4 launches).
// r4-trap mitigation: __launch_bounds__(256,1) full register budget + proj's
// explicit 2-stage pipeline forces liveness. TRIPWIRE: VGPR_Count ~24 =>
// trap re-fired, revert to separate kernels.
// ---------------------------------------------------------------------------
__global__ __launch_bounds__(256, 1) void prep_kernel(
    const float* __restrict__ x, const float* __restrict__ Wq,
    short* __restrict__ qb,
    const float* __restrict__ keys, const float* __restrict__ values,
    short* __restrict__ keys_sw, float* __restrict__ vpad) {
  if (blockIdx.x < PROJ_BLOCKS) {
    // ---- q = (x @ Wq^T) * QSCALE -> bf16, one 16x16 tile per wave ----
    const int wave = threadIdx.x >> 6, lane = threadIdx.x & 63;
    const int quad = lane >> 4, ln = lane & 15;
    const int tile = blockIdx.x * 4 + wave;      // 2048 tiles
    const int mt = tile >> 6, ot = tile & 63;    // 32 m-tiles x 64 o-tiles
    const float* xrow = x  + (mt * 16 + ln) * HIN_ + quad * 8;
    const float* wrow = Wq + (ot * 16 + ln) * HIN_ + quad * 8;
    float4v d = {0.f, 0.f, 0.f, 0.f};

    float4 xc[2][2], wc[2][2];                   // [stage][half], 32 VGPRs
#pragma unroll
    for (int s = 0; s < 2; ++s) {
      xc[s][0] = *(const float4*)(xrow + s * 32);
      xc[s][1] = *(const float4*)(xrow + s * 32 + 4);
      wc[s][0] = *(const float4*)(wrow + s * 32);
      wc[s][1] = *(const float4*)(wrow + s * 32 + 4);
    }
#pragma unroll
    for (int it = 0; it < 32; ++it) {            // k-chunk = 32 floats
      const int s = it & 1;
      float4 xa = xc[s][0], xb = xc[s][1];
      float4 wa = wc[s][0], wb = wc[s][1];
      const int kn = (it + 2) * 32;
      if (kn < HIN_) {                           // issue next-next chunk now
        xc[s][0] = *(const float4*)(xrow + kn);
        xc[s][1] = *(const float4*)(xrow + kn + 4);
        wc[s][0] = *(const float4*)(wrow + kn);
        wc[s][1] = *(const float4*)(wrow + kn + 4);
      }
      union { short8v s8; unsigned u[4]; } af, bf;
      af.u[0] = pk2(xa.x, xa.y); af.u[1] = pk2(xa.z, xa.w);
      af.u[2] = pk2(xb.x, xb.y); af.u[3] = pk2(xb.z, xb.w);
      bf.u[0] = pk2(wa.x, wa.y); bf.u[1] = pk2(wa.z, wa.w);
      bf.u[2] = pk2(wb.x, wb.y); bf.u[3] = pk2(wb.z, wb.w);
      d = __builtin_amdgcn_mfma_f32_16x16x32_bf16(af.s8, bf.s8, d, 0, 0, 0);
    }
#pragma unroll
    for (int r2 = 0; r2 < 4; ++r2)
      qb[(mt * 16 + quad * 4 + r2) * HIN_ + ot * 16 + ln] = f2bf(d[r2] * QSCALE);
  } else {
    // ---- keys fp32 -> bf16, swizzle on the STORE side (dense loads) ----
    int idx = (blockIdx.x - PROJ_BLOCKS) * 256 + threadIdx.x;  // logical chunk
    int key = idx >> 4;
    int lc  = idx & 15;
    union { short8v s; unsigned u[4]; } o;
    if (key < NKEY_) {
      const float4* src = (const float4*)(keys + key * EMB_ + lc * 8);
      float4 v0 = src[0], v1 = src[1];
      o.u[0] = pk2(v0.x, v0.y); o.u[1] = pk2(v0.z, v0.w);
      o.u[2] = pk2(v1.x, v1.y); o.u[3] = pk2(v1.z, v1.w);
    } else {
      o.u[0] = 0; o.u[1] = 0; o.u[2] = 0; o.u[3] = 0;  // pad rows -> p=2^-44
    }
    int pc = lc ^ (key & 15);                    // physical chunk (involution)
    *(short8v*)(keys_sw + (key * 16 + pc) * 8) = o.s;
    if (lc == 0) vpad[key] = (key < NKEY_) ? values[key] : 0.f;
  }
}

// ---------------------------------------------------------------------------
// Kernel 1: flash-decoding attention. Grid (16 query-cols, 61 key-slices) =
// 976 blocks = 3.8/CU (resident cap 4/CU at VGPR 112 / LDS 32 KB) -- up from
// r6's 736/2.9 to give the VALU, MFMA, and staging phases of DIFFERENT waves
// something to overlap with (r6: Occ 17%, pipes serialized on critical path).
// Ping-pong LDS, one barrier per tile, register prefetch 2 tiles ahead.
// ---------------------------------------------------------------------------
__global__ __launch_bounds__(256) void attn_kernel(
    const short* __restrict__ qb,        // bf16 [NQ_][128]
    const short* __restrict__ keys_sw,   // bf16 [NPAD_][128], chunk-swizzled
    const float* __restrict__ vpad,      // [NPAD_]
    float* __restrict__ partials) {      // [NQ_][NSLICES_][2] = {l, acc}
  __shared__ __align__(16) short kt[2][64 * 128];   // 2 x 16 KB ping-pong
  const int t     = threadIdx.x;
  const int wave  = t >> 6;
  const int lane  = t & 63;
  const int quad  = lane >> 4;
  const int ln    = lane & 15;
  const int qbase = blockIdx.x * 256 + wave * 64;
  const int slice = blockIdx.y;
  const int tile0 = slice * TPS_;
  const int tile1 = (tile0 + TPS_ < TILES_TOT) ? (tile0 + TPS_) : TILES_TOT;

  short8v a[4][4];
#pragma unroll
  for (int sub = 0; sub < 4; ++sub)
#pragma unroll
    for (int ks = 0; ks < 4; ++ks)
      a[sub][ks] = *(const short8v*)(qb + (qbase + sub * 16 + ln) * EMB_ + ks * 32 + quad * 8);

  float lsum[4][4], asum[4][4];
#pragma unroll
  for (int i = 0; i < 4; ++i)
#pragma unroll
    for (int j = 0; j < 4; ++j) { lsum[i][j] = 0.f; asum[i][j] = 0.f; }

  short8v stage[4];                              // 64 B/thread prefetch window
  {                                              // preload tile0 -> buf0
    const short* src = keys_sw + tile0 * (64 * 128);
#pragma unroll
    for (int j = 0; j < 4; ++j)
      stage[j] = *(const short8v*)(src + (t + j * 256) * 8);
#pragma unroll
    for (int j = 0; j < 4; ++j)
      *(short8v*)(&kt[0][0] + (t + j * 256) * 8) = stage[j];
    const short* s1 = keys_sw + (tile0 + 1) * (64 * 128);  // prefetch tile0+1
#pragma unroll
    for (int j = 0; j < 4; ++j)                  // (tile0+1 <= 781: always in-bank)
      stage[j] = *(const short8v*)(s1 + (t + j * 256) * 8);
  }
  __syncthreads();

  for (int tile = tile0; tile < tile1; ++tile) {
    const int cur = (tile - tile0) & 1;
    if (tile + 1 < tile1) {                      // park prefetched tile+1
#pragma unroll
      for (int j = 0; j < 4; ++j)
        *(short8v*)(&kt[cur ^ 1][0] + (t + j * 256) * 8) = stage[j];
    }
    if (tile + 2 < tile1) {                      // issue tile+2 loads now
      const short* nsrc = keys_sw + (tile + 2) * (64 * 128);
#pragma unroll
      for (int j = 0; j < 4; ++j)
        stage[j] = *(const short8v*)(nsrc + (t + j * 256) * 8);
    }
#pragma unroll
    for (int nsub = 0; nsub < 4; ++nsub) {
      short8v b[4];
#pragma unroll
      for (int ks = 0; ks < 4; ++ks) {
        int kc = ks * 4 + quad;                  // logical 8-elem chunk
        b[ks] = *(const short8v*)(&kt[cur][0] + (nsub * 16 + ln) * EMB_ + ((kc ^ ln) * 8));
      }
      float v = vpad[tile * 64 + nsub * 16 + ln];
#pragma unroll
      for (int sub = 0; sub < 4; ++sub) {
        float4v d = {-SHIFT_, -SHIFT_, -SHIFT_, -SHIFT_};
#pragma unroll
        for (int ks = 0; ks < 4; ++ks)
          d = __builtin_amdgcn_mfma_f32_16x16x32_bf16(a[sub][ks], b[ks], d, 0, 0, 0);
#pragma unroll
        for (int r2 = 0; r2 < 4; ++r2) {
          float p = EXP2F(d[r2]);
          lsum[sub][r2] += p;
          asum[sub][r2] = fmaf(p, v, asum[sub][r2]);
        }
      }
    }
    __syncthreads();
  }

#pragma unroll
  for (int sub = 0; sub < 4; ++sub)
#pragma unroll
    for (int r2 = 0; r2 < 4; ++r2) {
      float L = lsum[sub][r2], A = asum[sub][r2];
#pragma unroll
      for (int m = 1; m < 16; m <<= 1) {
        L += __shfl_xor(L, m, 64);
        A += __shfl_xor(A, m, 64);
      }
      if (ln == 0) {
        int q = qbase + sub * 16 + quad * 4 + r2;
        partials[(q * NSLICES_ + slice) * 2 + 0] = L;
        partials[(q * NSLICES_ + slice) * 2 + 1] = A;
      }
    }
}

// ---------------------------------------------------------------------------
// Kernel 2: combine slice partials, mean over heads, add curiosity.
// 61 slices * 2 floats = 122 = 30 float4 + 2 scalars.
// ---------------------------------------------------------------------------
__global__ __launch_bounds__(256) void finalize_kernel(
    const float* __restrict__ partials, const float* __restrict__ cur,
    float* __restrict__ out) {
  int tid = blockIdx.x * 256 + threadIdx.x;      // 4096 threads
  int bt = tid >> 3, h = tid & 7;
  int q = bt * NHEADS + h;
  const float* base = partials + q * NSLICES_ * 2;
  const float4* p = (const float4*)base;
  float sl = 0.f, sa = 0.f;
#pragma unroll
  for (int i = 0; i < (NSLICES_ * 2) / 4; ++i) { // 30 float4
    float4 v = p[i];
    sl += v.x + v.z;
    sa += v.y + v.w;
  }
  sl += base[NSLICES_ * 2 - 2];                  // tail slice 60
  sa += base[NSLICES_ * 2 - 1];
  float r = sa / sl;
  r += __shfl_xor(r, 1, 64);
  r += __shfl_xor(r, 2, 64);
  r += __shfl_xor(r, 4, 64);
  if (h == 0) out[bt] = r * (1.f / NHEADS) + cur[bt];
}

// ---------------------------------------------------------------------------
extern "C" void kernel_launch(void* const* d_in, const int* in_sizes, int n_in,
                              void* d_out, int out_size, void* d_ws, size_t ws_size,
                              hipStream_t stream) {
  (void)in_sizes; (void)n_in; (void)out_size; (void)ws_size;
  const float* x      = (const float*)d_in[0];   // (4,128,1024)
  const float* cur    = (const float*)d_in[1];   // (4,128)
  const float* Wq     = (const float*)d_in[2];   // (1024,1024)
  const float* keys   = (const float*)d_in[3];   // (50000,128)
  const float* values = (const float*)d_in[4];   // (50000,)
  float* out = (float*)d_out;                    // (4,128,1) fp32

  // workspace layout (16B-aligned), 16,059,904 B total (<= 16.16 MB proven in r2)
  char* ws = (char*)d_ws;
  short* keys_sw = (short*)(ws);                        // 12,812,288 B
  float* vpad    = (float*)(ws + 12812288);             //    200,192 B
  short* qb      = (short*)(ws + 13012480);             //  1,048,576 B
  float* part    = (float*)(ws + 14061056);             //  1,998,848 B (61 slices)

  hipLaunchKernelGGL(prep_kernel, dim3(PROJ_BLOCKS + CONV_BLOCKS), dim3(256), 0, stream,
                     x, Wq, qb, keys, values, keys_sw, vpad);
  hipLaunchKernelGGL(attn_kernel, dim3(16, NSLICES_), dim3(256), 0, stream,
                     qb, keys_sw, vpad, part);
  hipLaunchKernelGGL(finalize_kernel, dim3(16), dim3(256), 0, stream, part, cur, out);
}